// Round 8
// baseline (181.687 us; speedup 1.0000x reference)
//
#include <hip/hip_runtime.h>
#include <hip/hip_bf16.h>
#include <math.h>

// Problem constants (match reference)
#define BB 8
#define LL 1024
#define DD 1024
#define KK 128
#define NTS 1000
#define VOCAB 160
#define NATOM 512
#define SCALE 0.08838834764831845f                 // 128^-0.5

typedef __attribute__((ext_vector_type(8))) short short8;   // 8 bf16 = 4 VGPRs
typedef __attribute__((ext_vector_type(4))) float f32x4;    // MFMA accumulator

__device__ __forceinline__ unsigned short f2bf(float x) {
    __hip_bfloat16 h = __float2bfloat16(x);   // RTNE
    return *reinterpret_cast<unsigned short*>(&h);
}
__device__ __forceinline__ float bf2f(unsigned short u) {
    return __uint_as_float(((unsigned int)u) << 16);
}

// ---------------------------------------------------------------------------
// Merged prep kernel (one dispatch, 2725 blocks) -- unchanged from R5..R7:
//   0..2047    : transpose+cast w1 / w2 -> W1t/W2t [n][k] bf16
//   2048..2207 : cast embed_table fp32 -> bf16
//   2208..2719 : cast atom_feat_table fp32 -> bf16
//   2720..2723 : v[d] = sum_c pos_emb_w[c] * pos_feature_w[c,d]
//   2724       : resolve is_molecule dtype
// ---------------------------------------------------------------------------
__global__ __launch_bounds__(256) void prep_kernel(
    const float* __restrict__ w1,
    const float* __restrict__ w2,
    const float* __restrict__ embed_f,
    const float* __restrict__ atom_f,
    const float* __restrict__ pos_emb_w,
    const float* __restrict__ pos_feature_w,
    const void*  __restrict__ is_mol_raw,
    unsigned short* __restrict__ W1t,
    unsigned short* __restrict__ W2t,
    unsigned short* __restrict__ embed_bf,
    unsigned short* __restrict__ atom_bf,
    float* __restrict__ v,
    int*   __restrict__ is_mol_out)
{
    __shared__ float tile[32][33];
    const int blk = blockIdx.x;

    if (blk < 2048) {
        const int which = blk >> 10;                   // 0 -> w1, 1 -> w2
        const int idx = blk & 1023;
        const float* in = which ? w2 : w1;
        unsigned short* out = which ? W2t : W1t;
        const int bx = (idx & 31) * 32, by = (idx >> 5) * 32;
        const int tx = threadIdx.x & 31, ty = threadIdx.x >> 5;  // 32 x 8
        #pragma unroll
        for (int r = 0; r < 32; r += 8)
            tile[ty + r][tx] = in[(size_t)(by + ty + r) * DD + bx + tx];
        __syncthreads();
        #pragma unroll
        for (int r = 0; r < 32; r += 8)
            out[(size_t)(bx + ty + r) * DD + by + tx] = f2bf(tile[tx][ty + r]);
    } else if (blk < 2208) {
        const int e = ((blk - 2048) * 256 + threadIdx.x) * 4;    // < 160*1024
        float4 vv = *(const float4*)&embed_f[e];
        ushort4 o = { f2bf(vv.x), f2bf(vv.y), f2bf(vv.z), f2bf(vv.w) };
        *(ushort4*)&embed_bf[e] = o;
    } else if (blk < 2720) {
        const int e = ((blk - 2208) * 256 + threadIdx.x) * 4;    // < 512*1024
        float4 vv = *(const float4*)&atom_f[e];
        ushort4 o = { f2bf(vv.x), f2bf(vv.y), f2bf(vv.z), f2bf(vv.w) };
        *(ushort4*)&atom_bf[e] = o;
    } else if (blk < 2724) {
        int d = (blk - 2720) * 256 + threadIdx.x;      // < 1024
        float acc = 0.0f;
        #pragma unroll 4
        for (int c = 0; c < KK; ++c)
            acc += pos_emb_w[c] * pos_feature_w[c * DD + d];
        v[d] = acc;
    } else {
        if (threadIdx.x == 0) {
            const int* ip = (const int*)is_mol_raw;
            const unsigned char* cp = (const unsigned char*)is_mol_raw;
            bool all_bin = true;
            for (int i = 0; i < BB; ++i) {
                int x = ip[i];
                if (x != 0 && x != 1) all_bin = false;
            }
            for (int i = 0; i < BB; ++i)
                is_mol_out[i] = all_bin ? (ip[i] != 0) : (cp[i] != 0);
        }
    }
}

// ---------------------------------------------------------------------------
// B-RESIDENT bf16 MFMA GEMM -- no K-loop barrier at all.
// The 32-col B-slab over the FULL K=1024 lives in LDS (66 KB, 2 blocks/CU);
// loaded once, one __syncthreads, then each wave streams MFMA A-fragments
// DIRECTLY from global (k-contiguous row-major => one b128 per fragment) and
// issues 32 back-to-back MFMAs per M-tile. No staging phases, no vmcnt(0)
// drains -- the compiler pipelines A-loads under MFMA via fine-grained vmcnt.
// Grid (32 n-slabs, 16 m-groups) = 512 blocks; block 256 thr = 4 waves in a
// 2x2 grid over each 32x32 M-tile; 2 M-tiles per block.
// MODE 0: A = time_table fp32 (cast in fragment load, rows clamped at NTS-1;
//         junk rows >=1000 never gathered), silu -> bf16 H.
// MODE 1: A = H bf16, bias only -> bf16 E.
// ---------------------------------------------------------------------------
template <int MODE>
__global__ __launch_bounds__(256) void gemm_bres(
    const void* __restrict__ Ap,
    const unsigned short* __restrict__ Bt,
    const float* __restrict__ bias,
    unsigned short* __restrict__ Cout)
{
    // rowstride 1032 ushorts = 516 dwords == 4 (mod 32): b128 access pattern
    // lands on the 8-accesses-per-bank minimum (same class R6 measured at 0).
    __shared__ __align__(16) unsigned short Bs[32][1032];   // 66 KB

    const int tid  = threadIdx.x;
    const int lane = tid & 63;
    const int wave = tid >> 6;
    const int wm = wave >> 1, wn = wave & 1;
    const int quad = lane >> 4, l16 = lane & 15;
    const int nBase = blockIdx.x * 32;

    // ---- load the B-slab once: 32 rows (n) x 1024 k ------------------------
    {
        const int r = tid >> 3;                  // 0..31
        const int kb = (tid & 7) * 128;          // 8 threads per row
        #pragma unroll
        for (int c = 0; c < 16; ++c)
            *(float4*)&Bs[r][kb + c * 8] =
                *(const float4*)&Bt[(size_t)(nBase + r) * DD + kb + c * 8];
    }
    __syncthreads();

    const int col = nBase + wn * 16 + l16;
    const float bv = bias[col];
    const int kq = quad * 8;

    // ---- 2 M-tiles of 32 rows; zero barriers inside ------------------------
    #pragma unroll
    for (int mt = 0; mt < 2; ++mt) {
        const int mBase = blockIdx.y * 64 + mt * 32;
        int rowA = mBase + wm * 16 + l16;
        if (MODE == 0 && rowA >= NTS) rowA = NTS - 1;   // clamp pad rows

        f32x4 acc = {0.f, 0.f, 0.f, 0.f};

        #pragma unroll 4
        for (int kk = 0; kk < DD; kk += 32) {
            short8 af;
            if (MODE == 0) {
                const float* A = (const float*)Ap;
                float4 a0 = *(const float4*)&A[(size_t)rowA * DD + kk + kq];
                float4 a1 = *(const float4*)&A[(size_t)rowA * DD + kk + kq + 4];
                af[0]=f2bf(a0.x); af[1]=f2bf(a0.y); af[2]=f2bf(a0.z); af[3]=f2bf(a0.w);
                af[4]=f2bf(a1.x); af[5]=f2bf(a1.y); af[6]=f2bf(a1.z); af[7]=f2bf(a1.w);
            } else {
                const unsigned short* A = (const unsigned short*)Ap;
                af = *(const short8*)&A[(size_t)rowA * DD + kk + kq];
            }
            short8 bf = *(const short8*)&Bs[wn * 16 + l16][kk + kq];
            acc = __builtin_amdgcn_mfma_f32_16x16x32_bf16(af, bf, acc, 0, 0, 0);
        }

        // C/D layout: col = lane&15, row = quad*4 + reg  [m89-verified]
        #pragma unroll
        for (int r4 = 0; r4 < 4; ++r4) {
            const int row = mBase + wm * 16 + quad * 4 + r4;
            float val = acc[r4] + bv;
            if (MODE == 0) val = val / (1.0f + __expf(-val));   // silu
            Cout[(size_t)row * DD + col] = f2bf(val);
        }
    }
}

// ---------------------------------------------------------------------------
// Fused attention + assembly -- unchanged from R5..R7 (passing).
// ---------------------------------------------------------------------------
__global__ __launch_bounds__(256) void fused_all(
    const int*   __restrict__ token_id,
    const int*   __restrict__ node_attr,
    const float* __restrict__ pos,
    const int*   __restrict__ time_step,
    const unsigned short* __restrict__ embed_bf,
    const unsigned short* __restrict__ atom_bf,
    const unsigned short* __restrict__ Ebf,   // [1024, D] bf16 (rows >=1000 junk)
    const float* __restrict__ v,              // [D] fp32
    const int*   __restrict__ is_mol,         // [B] resolved 0/1
    float* __restrict__ out)
{
    __shared__ float4 keys[LL];               // 16 KB
    __shared__ float  sS[8];

    const int blk   = blockIdx.x;             // 0..1023
    const int batch = blk >> 7;
    const int q0    = (blk & 127) << 3;       // 8 queries per block
    const int tid   = threadIdx.x;
    const int lane  = tid & 63, wave = tid >> 6;

    // ---- stage keys --------------------------------------------------------
    #pragma unroll
    for (int i = 0; i < 4; ++i) {
        const int k = tid + i * 256;
        const int t = batch * LL + k;
        const float x = pos[t * 3 + 0];
        const float y = pos[t * 3 + 1];
        const float z = pos[t * 3 + 2];
        const int tok = token_id[t];
        const float n = sqrtf(x * x + y * y + z * z);
        keys[k] = make_float4(x, y, z, tok == 0 ? -1.0f : n);
    }
    __syncthreads();

    // ---- Phase A: s per query (wave handles 2 queries) ---------------------
    #pragma unroll
    for (int qi = 0; qi < 2; ++qi) {
        const int ql = wave * 2 + qi;
        const float4 qk = keys[q0 + ql];      // broadcast read
        float lsum = 0.0f, lws = 0.0f;
        #pragma unroll 4
        for (int i = 0; i < 16; ++i) {
            const float4 kd = keys[lane + i * 64];
            const float dx = qk.x - kd.x, dy = qk.y - kd.y, dz = qk.z - kd.z;
            const float dn = sqrtf(dx * dx + dy * dy + dz * dz);
            const float e = __expf(SCALE / (dn + 1.0f));
            const bool valid = kd.w >= 0.0f;
            const float ev = valid ? e : 0.0f;
            lsum += ev;
            lws  += ev * (valid ? kd.w : 0.0f);
        }
        #pragma unroll
        for (int off = 32; off > 0; off >>= 1) {
            lsum += __shfl_xor(lsum, off);
            lws  += __shfl_xor(lws,  off);
        }
        if (lane == 0)
            sS[ql] = (qk.w < 0.0f) ? 0.0f : (lws / lsum);
    }
    __syncthreads();

    // ---- Phase B: 8 output rows; 2 queries in parallel across halves -------
    const int im   = is_mol[batch];
    const int half = tid >> 7;                 // 0/1
    const int tl   = tid & 127;
    const int j    = tl * 8;                   // 128 thr x 8 dims = 1024
    const float4 v0 = *(const float4*)&v[j];
    const float4 v1 = *(const float4*)&v[j + 4];

    #pragma unroll
    for (int qp = 0; qp < 4; ++qp) {
        const int ql  = qp * 2 + half;
        const int t   = batch * LL + q0 + ql;
        const int tok = token_id[t];
        const int ts  = time_step[t];
        const float s = sS[ql];

        float o[8];
        short8 eb = *(const short8*)&embed_bf[(size_t)tok * DD + j];
        #pragma unroll
        for (int d = 0; d < 8; ++d) o[d] = bf2f((unsigned short)eb[d]);

        if (im) {
            #pragma unroll
            for (int f = 1; f < 9; ++f) {
                const int a = node_attr[t * 9 + f];
                short8 ab = *(const short8*)&atom_bf[(size_t)a * DD + j];
                #pragma unroll
                for (int d = 0; d < 8; ++d) o[d] += bf2f((unsigned short)ab[d]);
            }
        }
        short8 er = *(const short8*)&Ebf[(size_t)ts * DD + j];
        #pragma unroll
        for (int d = 0; d < 8; ++d) o[d] += bf2f((unsigned short)er[d]);

        o[0] += s * v0.x; o[1] += s * v0.y; o[2] += s * v0.z; o[3] += s * v0.w;
        o[4] += s * v1.x; o[5] += s * v1.y; o[6] += s * v1.z; o[7] += s * v1.w;

        float4 w0 = {o[0], o[1], o[2], o[3]};
        float4 w1 = {o[4], o[5], o[6], o[7]};
        *(float4*)&out[(size_t)t * DD + j]     = w0;
        *(float4*)&out[(size_t)t * DD + j + 4] = w1;
    }

    if (tid < 8) {
        const int t = batch * LL + q0 + tid;
        out[(size_t)BB * LL * DD + t] = (keys[q0 + tid].w < 0.0f) ? 1.0f : 0.0f;
    }
}

// ---------------------------------------------------------------------------
extern "C" void kernel_launch(void* const* d_in, const int* in_sizes, int n_in,
                              void* d_out, int out_size, void* d_ws, size_t ws_size,
                              hipStream_t stream)
{
    const int*   token_id      = (const int*)  d_in[0];
    const int*   node_attr     = (const int*)  d_in[1];
    const void*  is_mol_raw    = (const void*) d_in[2];
    const float* pos           = (const float*)d_in[3];
    const int*   time_step     = (const int*)  d_in[4];
    const float* embed_table   = (const float*)d_in[5];
    const float* atom_feat     = (const float*)d_in[6];
    const float* time_table    = (const float*)d_in[7];
    const float* w1            = (const float*)d_in[8];
    const float* b1            = (const float*)d_in[9];
    const float* w2            = (const float*)d_in[10];
    const float* b2            = (const float*)d_in[11];
    const float* pos_emb_w     = (const float*)d_in[12];
    const float* pos_feature_w = (const float*)d_in[13];

    float* out = (float*)d_out;
    char*  ws  = (char*)d_ws;

    // Workspace overlay (~7.5 MB) -- unchanged from R5..R7:
    //   [0,2MB):      W1t bf16 (dead after GEMM1) -> Ebf bf16 (GEMM2 out)
    //   [2MB,4MB):    H bf16
    //   [4MB,6MB):    W2t bf16
    //   [6MB,+320KB): embed_bf
    //   [6.5MB,+1MB): atom_bf
    //   [7.5MB,..):   V fp32[1024], is_mol int[8]
    unsigned short* W1t      = (unsigned short*)(ws);
    unsigned short* Ebf      = (unsigned short*)(ws);
    unsigned short* H        = (unsigned short*)(ws + (2u << 20));
    unsigned short* W2t      = (unsigned short*)(ws + (4u << 20));
    unsigned short* embed_bf = (unsigned short*)(ws + (6u << 20));
    unsigned short* atom_bf  = (unsigned short*)(ws + (6u << 20) + (512u << 10));
    float*          V        = (float*)(ws + (7u << 20) + (512u << 10));
    int*            is_mol_r = (int*)(V + 1024);

    prep_kernel<<<2725, 256, 0, stream>>>(w1, w2, embed_table, atom_feat,
                                          pos_emb_w, pos_feature_w, is_mol_raw,
                                          W1t, W2t, embed_bf, atom_bf,
                                          V, is_mol_r);

    dim3 g(32, 16);   // 32 n-slabs x 16 m-groups (64 rows each)
    gemm_bres<0><<<g, 256, 0, stream>>>((const void*)time_table, W1t, b1, H);
    gemm_bres<1><<<g, 256, 0, stream>>>((const void*)H,          W2t, b2, Ebf);

    fused_all<<<1024, 256, 0, stream>>>(token_id, node_attr, pos, time_step,
                                        embed_bf, atom_bf, Ebf, V,
                                        is_mol_r, out);
}

// Round 10
// 144.810 us; speedup vs baseline: 1.2547x; 1.2547x over previous
//
#include <hip/hip_runtime.h>
#include <hip/hip_bf16.h>
#include <math.h>

// Problem constants (match reference)
#define BB 8
#define LL 1024
#define DD 1024
#define KK 128
#define NTS 1000
#define SCALE 0.08838834764831845f                 // 128^-0.5

typedef __attribute__((ext_vector_type(8))) short short8;   // 8 bf16 = 4 VGPRs
typedef __attribute__((ext_vector_type(4))) float f32x4;    // MFMA accumulator

__device__ __forceinline__ unsigned short f2bf(float x) {
    __hip_bfloat16 h = __float2bfloat16(x);   // RTNE
    return *reinterpret_cast<unsigned short*>(&h);
}
__device__ __forceinline__ float bf2f(unsigned short u) {
    return __uint_as_float(((unsigned int)u) << 16);
}

// Per-phase LDS union (17.4 KB max)
union SMem {
    struct { unsigned short As[32][136]; unsigned short Bs[32][136]; } g;  // 17408 B
    float4 keys[LL];                                                        // 16384 B
    float  tile[32][33];                                                    // 4224 B
};

// ---------------------------------------------------------------------------
// 32x32 transpose+cast tile: in fp32 [1024,1024] -> out[n][k] bf16 (R6-proven)
// ---------------------------------------------------------------------------
__device__ __forceinline__ void transpose_tile(
    const float* __restrict__ in, unsigned short* __restrict__ out,
    int idx, SMem& sm)
{
    const int tid = threadIdx.x;
    const int bx = (idx & 31) * 32, by = (idx >> 5) * 32;
    const int tx = tid & 31, ty = tid >> 5;   // 32 x 8
    #pragma unroll
    for (int r = 0; r < 32; r += 8)
        sm.tile[ty + r][tx] = in[(size_t)(by + ty + r) * DD + bx + tx];
    __syncthreads();
    #pragma unroll
    for (int r = 0; r < 32; r += 8)
        out[(size_t)(bx + ty + r) * DD + by + tx] = f2bf(sm.tile[tx][ty + r]);
}

// ---------------------------------------------------------------------------
// R6-proven 32x32-tile BK=128 MFMA GEMM K-loop (one tile).
// Af != nullptr: A fp32, cast in staging, rows clamped at NTS-1 (junk rows
// >=1000 never gathered). Else A = Ab bf16. do_silu: silu epilogue. bf16 out.
// ---------------------------------------------------------------------------
__device__ __forceinline__ void gemm32_tile(
    const float* __restrict__ Af, const unsigned short* __restrict__ Ab,
    const unsigned short* __restrict__ Bt, const float* __restrict__ bias,
    unsigned short* __restrict__ Cout, int mBase, int nBase, int do_silu,
    SMem& sm)
{
    const int tid  = threadIdx.x;
    const int lane = tid & 63, wave = tid >> 6;
    const int wm = wave >> 1, wn = wave & 1;
    const int quad = lane >> 4, l16 = lane & 15;

    f32x4 acc = {0.f, 0.f, 0.f, 0.f};

    const int r0 = tid >> 4, ko = (tid & 15) * 8;   // 16 thr/row; rows r0, r0+16
    const int rowB0 = nBase + r0, rowB1 = nBase + r0 + 16;
    int rowA0 = mBase + r0, rowA1 = mBase + r0 + 16;
    if (Af) {
        if (rowA0 >= NTS) rowA0 = NTS - 1;
        if (rowA1 >= NTS) rowA1 = NTS - 1;
    }

    for (int k0 = 0; k0 < DD; k0 += 128) {
        if (Af) {
            float4 a00 = *(const float4*)&Af[(size_t)rowA0 * DD + k0 + ko];
            float4 a01 = *(const float4*)&Af[(size_t)rowA0 * DD + k0 + ko + 4];
            float4 a10 = *(const float4*)&Af[(size_t)rowA1 * DD + k0 + ko];
            float4 a11 = *(const float4*)&Af[(size_t)rowA1 * DD + k0 + ko + 4];
            short8 s0, s1;
            s0[0]=f2bf(a00.x); s0[1]=f2bf(a00.y); s0[2]=f2bf(a00.z); s0[3]=f2bf(a00.w);
            s0[4]=f2bf(a01.x); s0[5]=f2bf(a01.y); s0[6]=f2bf(a01.z); s0[7]=f2bf(a01.w);
            s1[0]=f2bf(a10.x); s1[1]=f2bf(a10.y); s1[2]=f2bf(a10.z); s1[3]=f2bf(a10.w);
            s1[4]=f2bf(a11.x); s1[5]=f2bf(a11.y); s1[6]=f2bf(a11.z); s1[7]=f2bf(a11.w);
            *(short8*)&sm.g.As[r0][ko]      = s0;
            *(short8*)&sm.g.As[r0 + 16][ko] = s1;
        } else {
            float4 a0 = *(const float4*)&Ab[(size_t)rowA0 * DD + k0 + ko];
            float4 a1 = *(const float4*)&Ab[(size_t)rowA1 * DD + k0 + ko];
            *(float4*)&sm.g.As[r0][ko]      = a0;
            *(float4*)&sm.g.As[r0 + 16][ko] = a1;
        }
        float4 b0 = *(const float4*)&Bt[(size_t)rowB0 * DD + k0 + ko];
        float4 b1 = *(const float4*)&Bt[(size_t)rowB1 * DD + k0 + ko];
        *(float4*)&sm.g.Bs[r0][ko]      = b0;
        *(float4*)&sm.g.Bs[r0 + 16][ko] = b1;
        __syncthreads();

        #pragma unroll
        for (int kk = 0; kk < 128; kk += 32) {
            short8 af = *(const short8*)&sm.g.As[wm * 16 + l16][kk + quad * 8];
            short8 bf = *(const short8*)&sm.g.Bs[wn * 16 + l16][kk + quad * 8];
            acc = __builtin_amdgcn_mfma_f32_16x16x32_bf16(af, bf, acc, 0, 0, 0);
        }
        __syncthreads();
    }

    // C/D layout: col = lane&15, row = quad*4 + reg  [m89-verified]
    const int col = nBase + wn * 16 + l16;
    const float bv = bias[col];
    #pragma unroll
    for (int r4 = 0; r4 < 4; ++r4) {
        const int row = mBase + wm * 16 + quad * 4 + r4;
        float val = acc[r4] + bv;
        if (do_silu) val = val / (1.0f + __expf(-val));
        Cout[(size_t)row * DD + col] = f2bf(val);
    }
}

// ---------------------------------------------------------------------------
// K1: w1 -> W1t only (1024 tile-blocks). Everything else moves to K2's shadow.
// ---------------------------------------------------------------------------
__global__ __launch_bounds__(256) void prep1(
    const float* __restrict__ w1, unsigned short* __restrict__ W1t)
{
    __shared__ SMem sm;
    transpose_tile(w1, W1t, blockIdx.x, sm);
}

// ---------------------------------------------------------------------------
// K2: gemm1 (blocks 0..1023) + all gemm1-independent work co-scheduled:
//   1024..2047 : w2 -> W2t transpose tiles
//   2048..2207 : embed cast fp32->bf16
//   2208..2719 : atom cast fp32->bf16
//   2720..2723 : v[d] = sum_c pos_emb_w[c] * pos_feature_w[c,d]
//   2724       : is_molecule dtype resolve
//   2725..3236 : attention scalars (512 blocks x 16 queries -> sSg)
// The memory-bound filler blocks hide in gemm1's latency bubbles (m114:
// inter-wave MFMA/VALU co-scheduling is free).
// ---------------------------------------------------------------------------
__global__ __launch_bounds__(256) void mid(
    const float* __restrict__ time_table,
    const unsigned short* __restrict__ W1t,
    const float* __restrict__ b1,
    const float* __restrict__ w2,
    const float* __restrict__ embed_f,
    const float* __restrict__ atom_f,
    const float* __restrict__ pos_emb_w,
    const float* __restrict__ pos_feature_w,
    const void*  __restrict__ is_mol_raw,
    const int*   __restrict__ token_id,
    const float* __restrict__ pos,
    unsigned short* __restrict__ H,
    unsigned short* __restrict__ W2t,
    unsigned short* __restrict__ embed_bf,
    unsigned short* __restrict__ atom_bf,
    float* __restrict__ v,
    int*   __restrict__ is_mol_out,
    float* __restrict__ sSg)
{
    __shared__ SMem sm;
    const int blk = blockIdx.x;
    const int tid = threadIdx.x;

    if (blk < 1024) {
        gemm32_tile(time_table, nullptr, W1t, b1, H,
                    (blk >> 5) * 32, (blk & 31) * 32, 1, sm);
    } else if (blk < 2048) {
        transpose_tile(w2, W2t, blk - 1024, sm);
    } else if (blk < 2208) {
        const int e = ((blk - 2048) * 256 + tid) * 4;    // < 160*1024
        float4 vv = *(const float4*)&embed_f[e];
        ushort4 o = { f2bf(vv.x), f2bf(vv.y), f2bf(vv.z), f2bf(vv.w) };
        *(ushort4*)&embed_bf[e] = o;
    } else if (blk < 2720) {
        const int e = ((blk - 2208) * 256 + tid) * 4;    // < 512*1024
        float4 vv = *(const float4*)&atom_f[e];
        ushort4 o = { f2bf(vv.x), f2bf(vv.y), f2bf(vv.z), f2bf(vv.w) };
        *(ushort4*)&atom_bf[e] = o;
    } else if (blk < 2724) {
        const int d = (blk - 2720) * 256 + tid;          // < 1024
        float acc = 0.0f;
        #pragma unroll 4
        for (int c = 0; c < KK; ++c)
            acc += pos_emb_w[c] * pos_feature_w[c * DD + d];
        v[d] = acc;
    } else if (blk == 2724) {
        if (tid == 0) {
            const int* ip = (const int*)is_mol_raw;
            const unsigned char* cp = (const unsigned char*)is_mol_raw;
            bool all_bin = true;
            for (int i = 0; i < BB; ++i) {
                int x = ip[i];
                if (x != 0 && x != 1) all_bin = false;
            }
            for (int i = 0; i < BB; ++i)
                is_mol_out[i] = all_bin ? (ip[i] != 0) : (cp[i] != 0);
        }
    } else {
        // Attention scalars: block handles 16 queries of one batch.
        // No-max softmax: valid scores in (0, 0.0884] so exp can't overflow;
        // masked keys contribute exactly 0 (reference: exp(NEG*SCALE-gmax)==0).
        const int ab = blk - 2725;            // 0..511
        const int batch = ab >> 6;
        const int q0 = (ab & 63) * 16;
        const int lane = tid & 63, wave = tid >> 6;

        #pragma unroll
        for (int i = 0; i < 4; ++i) {
            const int k = tid + i * 256;
            const int t = batch * LL + k;
            const float x = pos[t * 3 + 0];
            const float y = pos[t * 3 + 1];
            const float z = pos[t * 3 + 2];
            const int tok = token_id[t];
            const float n = sqrtf(x * x + y * y + z * z);
            sm.keys[k] = make_float4(x, y, z, tok == 0 ? -1.0f : n);
        }
        __syncthreads();

        #pragma unroll
        for (int qi = 0; qi < 4; ++qi) {
            const int ql = wave * 4 + qi;
            const float4 qk = sm.keys[q0 + ql];
            float lsum = 0.0f, lws = 0.0f;
            #pragma unroll 4
            for (int i = 0; i < 16; ++i) {
                const float4 kd = sm.keys[lane + i * 64];
                const float dx = qk.x - kd.x, dy = qk.y - kd.y, dz = qk.z - kd.z;
                const float dn = sqrtf(dx * dx + dy * dy + dz * dz);
                const float e = __expf(SCALE / (dn + 1.0f));
                const bool valid = kd.w >= 0.0f;
                const float ev = valid ? e : 0.0f;
                lsum += ev;
                lws  += ev * (valid ? kd.w : 0.0f);
            }
            #pragma unroll
            for (int off = 32; off > 0; off >>= 1) {
                lsum += __shfl_xor(lsum, off);
                lws  += __shfl_xor(lws,  off);
            }
            if (lane == 0)
                sSg[batch * LL + q0 + ql] = (qk.w < 0.0f) ? 0.0f : (lws / lsum);
        }
    }
}

// ---------------------------------------------------------------------------
// K3: gemm2 (1024 tile-blocks): Ebf = H @ W2t + b2 (bf16 out).
// ---------------------------------------------------------------------------
__global__ __launch_bounds__(256) void gemm2k(
    const unsigned short* __restrict__ H,
    const unsigned short* __restrict__ W2t,
    const float* __restrict__ b2,
    unsigned short* __restrict__ Ebf)
{
    __shared__ SMem sm;
    gemm32_tile(nullptr, H, W2t, b2, Ebf,
                (blockIdx.x >> 5) * 32, (blockIdx.x & 31) * 32, 0, sm);
}

// ---------------------------------------------------------------------------
// K4: gather/assemble only (Phase B of R6's fused_all; s from sSg).
// 1024 blocks x 256 thr; block = 8 queries; 2 queries across thread halves.
// ---------------------------------------------------------------------------
__global__ __launch_bounds__(256) void assemble(
    const int*   __restrict__ token_id,
    const int*   __restrict__ node_attr,
    const int*   __restrict__ time_step,
    const unsigned short* __restrict__ embed_bf,
    const unsigned short* __restrict__ atom_bf,
    const unsigned short* __restrict__ Ebf,
    const float* __restrict__ v,
    const float* __restrict__ sSg,
    const int*   __restrict__ is_mol,
    float* __restrict__ out)
{
    const int blk   = blockIdx.x;
    const int batch = blk >> 7;
    const int q0    = (blk & 127) << 3;
    const int tid   = threadIdx.x;

    const int im   = is_mol[batch];
    const int half = tid >> 7;
    const int tl   = tid & 127;
    const int j    = tl * 8;
    const float4 v0 = *(const float4*)&v[j];
    const float4 v1 = *(const float4*)&v[j + 4];

    #pragma unroll
    for (int qp = 0; qp < 4; ++qp) {
        const int ql  = qp * 2 + half;
        const int t   = batch * LL + q0 + ql;
        const int tok = token_id[t];
        const int ts  = time_step[t];
        const float s = sSg[t];

        float o[8];
        short8 eb = *(const short8*)&embed_bf[(size_t)tok * DD + j];
        #pragma unroll
        for (int d = 0; d < 8; ++d) o[d] = bf2f((unsigned short)eb[d]);

        if (im) {
            #pragma unroll
            for (int f = 1; f < 9; ++f) {
                const int a = node_attr[t * 9 + f];
                short8 ab = *(const short8*)&atom_bf[(size_t)a * DD + j];
                #pragma unroll
                for (int d = 0; d < 8; ++d) o[d] += bf2f((unsigned short)ab[d]);
            }
        }
        short8 er = *(const short8*)&Ebf[(size_t)ts * DD + j];
        #pragma unroll
        for (int d = 0; d < 8; ++d) o[d] += bf2f((unsigned short)er[d]);

        o[0] += s * v0.x; o[1] += s * v0.y; o[2] += s * v0.z; o[3] += s * v0.w;
        o[4] += s * v1.x; o[5] += s * v1.y; o[6] += s * v1.z; o[7] += s * v1.w;

        float4 wlo = {o[0], o[1], o[2], o[3]};
        float4 whi = {o[4], o[5], o[6], o[7]};
        *(float4*)&out[(size_t)t * DD + j]     = wlo;
        *(float4*)&out[(size_t)t * DD + j + 4] = whi;
    }

    if (tid < 8) {
        const int t = batch * LL + q0 + tid;
        out[(size_t)BB * LL * DD + t] = (token_id[t] == 0) ? 1.0f : 0.0f;
    }
}

// ---------------------------------------------------------------------------
extern "C" void kernel_launch(void* const* d_in, const int* in_sizes, int n_in,
                              void* d_out, int out_size, void* d_ws, size_t ws_size,
                              hipStream_t stream)
{
    const int*   token_id      = (const int*)  d_in[0];
    const int*   node_attr     = (const int*)  d_in[1];
    const void*  is_mol_raw    = (const void*) d_in[2];
    const float* pos           = (const float*)d_in[3];
    const int*   time_step     = (const int*)  d_in[4];
    const float* embed_table   = (const float*)d_in[5];
    const float* atom_feat     = (const float*)d_in[6];
    const float* time_table    = (const float*)d_in[7];
    const float* w1            = (const float*)d_in[8];
    const float* b1            = (const float*)d_in[9];
    const float* w2            = (const float*)d_in[10];
    const float* b2            = (const float*)d_in[11];
    const float* pos_emb_w     = (const float*)d_in[12];
    const float* pos_feature_w = (const float*)d_in[13];

    float* out = (float*)d_out;
    char*  ws  = (char*)d_ws;

    // Workspace overlay (~7.54 MB, under proven 8.43 MB):
    //   [0,2MB):      W1t bf16 (dead after K2) -> Ebf bf16 (K3 out)
    //   [2MB,4MB):    H bf16
    //   [4MB,6MB):    W2t bf16
    //   [6MB,+320KB): embed_bf
    //   [6.5MB,+1MB): atom_bf
    //   [7.5MB,..):   V fp32[1024] | sSg fp32[8192] | is_mol int[8]
    unsigned short* W1t      = (unsigned short*)(ws);
    unsigned short* Ebf      = (unsigned short*)(ws);
    unsigned short* H        = (unsigned short*)(ws + (2u << 20));
    unsigned short* W2t      = (unsigned short*)(ws + (4u << 20));
    unsigned short* embed_bf = (unsigned short*)(ws + (6u << 20));
    unsigned short* atom_bf  = (unsigned short*)(ws + (6u << 20) + (512u << 10));
    char*           base7    = ws + (7u << 20) + (512u << 10);
    float*          V        = (float*)(base7);
    float*          sSg      = (float*)(base7 + (4u << 10));
    int*            is_mol_r = (int*)  (base7 + (36u << 10));

    prep1<<<1024, 256, 0, stream>>>(w1, W1t);

    mid<<<3237, 256, 0, stream>>>(time_table, W1t, b1, w2, embed_table,
                                  atom_feat, pos_emb_w, pos_feature_w,
                                  is_mol_raw, token_id, pos,
                                  H, W2t, embed_bf, atom_bf, V, is_mol_r, sSg);

    gemm2k<<<1024, 256, 0, stream>>>(H, W2t, b2, Ebf);

    assemble<<<1024, 256, 0, stream>>>(token_id, node_attr, time_step,
                                       embed_bf, atom_bf, Ebf, V, sSg,
                                       is_mol_r, out);
}